// Round 2
// baseline (2487.288 us; speedup 1.0000x reference)
//
#include <hip/hip_runtime.h>
#include <hip/hip_bf16.h>
#include <math.h>

// DAGNN r12:
//  - spmm restructured as a source-range sweep for per-XCD L2 residency:
//    CSR keyed range-major (key = r*N + dest, 8 ranges of 16384 src nodes =
//    2.0 MB bf16 rows). All waves sweep ranges in order; co-resident grid
//    (1250 blocks, 5/CU) keeps each XCD's L2 on one range at a time ->
//    gathers served at L2 BW (~34.5 TB/s) instead of mixed L2/L3 (~6 TB/s).
//    Each wave owns 20 dests, acc in registers (32-lane rows, 2 f32/dest).
//  - build passes extended: cnt2/offs2 over (range, dest) keys.
//  - mlp_fused unchanged from r10/r11.

#define WAVE 64
#define NBLK 1024   // blocks in passA/passB; must match between them
#define RS 520      // LDS region stride in ushorts (64*8 + 8 pad)
#define NR 8        // source ranges
#define RSH 14      // range = src >> RSH (16384 nodes/range)
#define DPW 20      // dests per wave in spmm2

__device__ inline float bf2f(unsigned short u) {
    union { unsigned int i; float f; } v; v.i = ((unsigned int)u) << 16; return v.f;
}
__device__ inline unsigned short f2bf(float f) {
    __hip_bfloat16 b = __float2bfloat16(f);
    union { __hip_bfloat16 b; unsigned short u; } v; v.b = b; return v.u;
}
__device__ inline float bflo(unsigned u) {
    union { unsigned i; float f; } v; v.i = u << 16; return v.f;
}
__device__ inline float bfhi(unsigned u) {
    union { unsigned i; float f; } v; v.i = u & 0xffff0000u; return v.f;
}

typedef __attribute__((ext_vector_type(8))) short bf16x8;
typedef __attribute__((ext_vector_type(16))) float f32x16;

// ---- edge dtype detection: stride 1 (int32) or 2 (int64 low words) ----
__global__ void detect_kernel(const unsigned* __restrict__ e, int* __restrict__ sflag) {
    __shared__ int any;
    if (threadIdx.x == 0) any = 0;
    __syncthreads();
    unsigned nz = 0;
    int t = threadIdx.x;
    for (int i = 0; i < 8; ++i) nz |= e[(size_t)(t * 8 + i) * 2 + 1];
    if (nz) atomicOr(&any, 1);
    __syncthreads();
    if (t == 0) *sflag = any ? 1 : 2;
}

// ---- passA: per-block LDS bucket histogram; blk_cnt[blk][bucket] ----
__global__ void passA_kernel(const int* __restrict__ eidx, const int* __restrict__ sflag,
                             int* __restrict__ blk_cnt, int E, int NB, int EPB) {
    __shared__ int lh[512];
    int t = threadIdx.x, blk = blockIdx.x;
    for (int i = t; i < NB; i += 256) lh[i] = 0;
    __syncthreads();
    int s = *sflag;
    int base = blk * EPB;
    int end = base + EPB; if (end > E) end = E;
    for (int e = base + t; e < end; e += 256) {
        int c = eidx[(size_t)s * (size_t)(E + e)];
        atomicAdd(&lh[c >> 8], 1);
    }
    __syncthreads();
    for (int i = t; i < NB; i += 256)
        blk_cnt[(size_t)blk * NB + i] = lh[i];
}

// ---- scans ----
__global__ void scan1_kernel(const int* __restrict__ in, int* __restrict__ out,
                             int* __restrict__ bsums, int n) {
    __shared__ int s[256];
    int t = threadIdx.x;
    int idx = blockIdx.x * 1024 + t * 4;
    int x0 = (idx + 0 < n) ? in[idx + 0] : 0;
    int x1 = (idx + 1 < n) ? in[idx + 1] : 0;
    int x2 = (idx + 2 < n) ? in[idx + 2] : 0;
    int x3 = (idx + 3 < n) ? in[idx + 3] : 0;
    int lsum = x0 + x1 + x2 + x3;
    s[t] = lsum;
    __syncthreads();
    for (int o = 1; o < 256; o <<= 1) {
        int v = (t >= o) ? s[t - o] : 0;
        __syncthreads();
        if (t >= o) s[t] += v;
        __syncthreads();
    }
    int excl = s[t] - lsum;
    if (idx + 0 < n) out[idx + 0] = excl;
    if (idx + 1 < n) out[idx + 1] = excl + x0;
    if (idx + 2 < n) out[idx + 2] = excl + x0 + x1;
    if (idx + 3 < n) out[idx + 3] = excl + x0 + x1 + x2;
    if (t == 255) bsums[blockIdx.x] = s[255];
}

__global__ void scan2g_kernel(int* __restrict__ bsums, int nb) {
    __shared__ int part[256];
    int t = threadIdx.x;
    int v[4]; int run = 0;
    #pragma unroll
    for (int j = 0; j < 4; ++j) {
        int i = t * 4 + j;
        int x = (i < nb) ? bsums[i] : 0;
        v[j] = run; run += x;
    }
    part[t] = run;
    __syncthreads();
    for (int o = 1; o < 256; o <<= 1) {
        int x = (t >= o) ? part[t - o] : 0;
        __syncthreads();
        if (t >= o) part[t] += x;
        __syncthreads();
    }
    int excl = part[t] - run;
    #pragma unroll
    for (int j = 0; j < 4; ++j) {
        int i = t * 4 + j;
        if (i < nb) bsums[i] = excl + v[j];
    }
}

__global__ void scan3_kernel(int* __restrict__ arr, const int* __restrict__ bsums,
                             int n, int total) {
    int t = threadIdx.x;
    int idx = blockIdx.x * 1024 + t * 4;
    int add = bsums[blockIdx.x];
    #pragma unroll
    for (int i = 0; i < 4; ++i)
        if (idx + i < n) arr[idx + i] += add;
    if (blockIdx.x == 0 && t == 0) arr[n] = total;
}

// ---- passB: LDS-cursor pair scatter; windows block-major (dense per block) ----
__global__ void passB_kernel(const int* __restrict__ eidx, const int* __restrict__ sflag,
                             const int* __restrict__ pbase, int2* __restrict__ pairs,
                             int E, int NB, int EPB) {
    __shared__ int lcur[512];
    int t = threadIdx.x, blk = blockIdx.x;
    for (int i = t; i < NB; i += 256) lcur[i] = pbase[(size_t)blk * NB + i];
    __syncthreads();
    int s = *sflag;
    int base = blk * EPB;
    int end = base + EPB; if (end > E) end = E;
    for (int e = base + t; e < end; e += 256) {
        int r = eidx[(size_t)s * (size_t)e];
        int c = eidx[(size_t)s * (size_t)(E + e)];
        int pos = atomicAdd(&lcur[c >> 8], 1);
        pairs[pos] = make_int2(r, c);
    }
}

// ---- passD2: per-(range,node) counts into cnt2[r*N + node] ----
__global__ void passD2_kernel(const int2* __restrict__ pairs, const int* __restrict__ pbase,
                              int* __restrict__ cnt2, int N, int NB) {
    __shared__ int lcnt[256 * NR];
    int b = blockIdx.x, t = threadIdx.x;
    for (int i = t; i < 256 * NR; i += 256) lcnt[i] = 0;
    __syncthreads();
    for (int blk = t; blk < NBLK; blk += 256) {
        int w0 = pbase[(size_t)blk * NB + b];
        int w1 = pbase[(size_t)blk * NB + b + 1];
        for (int i = w0; i < w1; ++i) {
            int2 p = pairs[i];
            atomicAdd(&lcnt[((p.x >> RSH) << 8) | (p.y & 255)], 1);
        }
    }
    __syncthreads();
    for (int i = t; i < 256 * NR; i += 256) {
        int node = b * 256 + (i & 255);
        if (node < N) cnt2[(size_t)(i >> 8) * N + node] = lcnt[i];
    }
}

// ---- dinv from cnt2 (sum over ranges) ----
__global__ void dinv2_kernel(const int* __restrict__ cnt2, float* __restrict__ dinv, int n) {
    int i = blockIdx.x * blockDim.x + threadIdx.x;
    if (i >= n) return;
    int deg = 0;
    #pragma unroll
    for (int r = 0; r < NR; ++r) deg += cnt2[(size_t)r * n + i];
    dinv[i] = rsqrtf((float)(deg + 1));  // self-loop adds 1
}

// ---- passC2: per-(range,node) cursors, scatter src into CSR windows ----
__global__ void passC2_kernel(const int2* __restrict__ pairs, const int* __restrict__ pbase,
                              const int* __restrict__ offs2, int* __restrict__ csr_src,
                              int N, int NB) {
    __shared__ int lcur[256 * NR];
    int b = blockIdx.x, t = threadIdx.x;
    for (int i = t; i < 256 * NR; i += 256) {
        int node = b * 256 + (i & 255);
        lcur[i] = (node < N) ? offs2[(size_t)(i >> 8) * N + node] : 0;
    }
    __syncthreads();
    for (int blk = t; blk < NBLK; blk += 256) {
        int w0 = pbase[(size_t)blk * NB + b];
        int w1 = pbase[(size_t)blk * NB + b + 1];
        for (int i = w0; i < w1; ++i) {
            int2 p = pairs[i];
            int pos = atomicAdd(&lcur[((p.x >> RSH) << 8) | (p.y & 255)], 1);
            csr_src[pos] = p.x;
        }
    }
}

// ---- weight convert to fragment-major: Wf[(k>>3)*Nn*8 + n*8 + (k&7)] = bf16(W[k][n]) ----
__global__ void wconv_kernel(const float* __restrict__ W, unsigned short* __restrict__ Wf,
                             int K, int Nn) {
    int i = blockIdx.x * blockDim.x + threadIdx.x;
    if (i >= K * Nn) return;
    int k = i / Nn, n = i - k * Nn;
    Wf[(size_t)(k >> 3) * Nn * 8 + n * 8 + (k & 7)] = f2bf(W[i]);
}

// ---- fused MLP: h = relu(x@W1+b1)@W2+b2 ; out = sigmoid(h.pw+pb)*h ;
//      g0 = bf16(dinv*h).  BM=64 rows/block, 256 thr (4 waves). ----
__global__ __launch_bounds__(256, 4) void mlp_fused(
        const float* __restrict__ x,
        const unsigned short* __restrict__ W1f,   // frag-major [k>>3][256 n][8]
        const float* __restrict__ b1,
        const unsigned short* __restrict__ W2f,   // frag-major [k>>3][64 n][8]
        const float* __restrict__ b2,
        const float* __restrict__ dinv,
        const float* __restrict__ pw, const float* __restrict__ pb,
        float* __restrict__ out, unsigned short* __restrict__ g,
        int M) {
    __shared__ unsigned short xfrag[4 * RS];    // region = (k&31)>>3
    __shared__ unsigned short h1frag[32 * RS];  // region = ch>>3 (stage-2 k)
    __shared__ float pools[2][2][2][16];        // [rt2][ct2][half][reg]

    int tid = threadIdx.x;
    int wave = tid >> 6, lane = tid & 63;
    int half = lane >> 5, l31 = lane & 31;
    int rt = wave & 1;          // stage-1 row tile (32 rows)
    int cw = wave >> 1;         // stage-1 col half (128 cols)
    int bm = blockIdx.x * 64;

    f32x16 acc1[4] = {};

    float4 xv[2];
    #pragma unroll
    for (int i = 0; i < 2; ++i) {
        int f = i * 256 + tid;
        int row = f >> 3, c4 = (f & 7) * 4;
        int grow = bm + row;
        xv[i] = (grow < M) ? *(const float4*)(x + (size_t)grow * 256 + c4)
                           : make_float4(0.f, 0.f, 0.f, 0.f);
    }

    for (int it = 0; it < 8; ++it) {
        #pragma unroll
        for (int i = 0; i < 2; ++i) {
            int f = i * 256 + tid;
            int row = f >> 3, c4 = (f & 7) * 4;
            int region = c4 >> 3, off = c4 & 7;
            ushort4 u;
            u.x = f2bf(xv[i].x); u.y = f2bf(xv[i].y);
            u.z = f2bf(xv[i].z); u.w = f2bf(xv[i].w);
            *(ushort4*)&xfrag[region * RS + row * 8 + off] = u;
        }
        __syncthreads();
        if (it < 7) {
            int k0 = (it + 1) * 32;
            #pragma unroll
            for (int i = 0; i < 2; ++i) {
                int f = i * 256 + tid;
                int row = f >> 3, c4 = (f & 7) * 4;
                int grow = bm + row;
                xv[i] = (grow < M) ? *(const float4*)(x + (size_t)grow * 256 + k0 + c4)
                                   : make_float4(0.f, 0.f, 0.f, 0.f);
            }
        }
        // MFMAs; B fragments coalesced from global frag-major layout
        #pragma unroll
        for (int s = 0; s < 2; ++s) {
            int region = it * 4 + s * 2 + half;          // k>>3 of this fragment
            bf16x8 a = *(bf16x8*)&xfrag[(s * 2 + half) * RS + (rt * 32 + l31) * 8];
            #pragma unroll
            for (int j = 0; j < 4; ++j) {
                int ch = cw * 128 + j * 32 + l31;
                bf16x8 b = *(const bf16x8*)(W1f + (size_t)region * 2048 + ch * 8);
                acc1[j] = __builtin_amdgcn_mfma_f32_32x32x16_bf16(a, b, acc1[j], 0, 0, 0);
            }
        }
        __syncthreads();
    }

    // bias + relu, write h1 tile to LDS in stage-2 A-fragment layout
    #pragma unroll
    for (int j = 0; j < 4; ++j) {
        int ch = cw * 128 + j * 32 + l31;     // stage-2 k index
        float bb = b1[ch];
        int region = ch >> 3, off = ch & 7;
        #pragma unroll
        for (int reg = 0; reg < 16; ++reg) {
            int rowin = (reg & 3) + 8 * (reg >> 2) + 4 * half;
            int row = rt * 32 + rowin;
            float v = fmaxf(acc1[j][reg] + bb, 0.f);
            h1frag[region * RS + row * 8 + off] = f2bf(v);
        }
    }
    __syncthreads();

    // stage 2 on all 4 waves: wave = rt2*2 + ct2 tile (32 rows x 32 cols)
    int rt2 = wave >> 1, ct2 = wave & 1;
    f32x16 acc2 = {};
    #pragma unroll
    for (int s = 0; s < 16; ++s) {
        bf16x8 a = *(bf16x8*)&h1frag[(s * 2 + half) * RS + (rt2 * 32 + l31) * 8];
        bf16x8 b = *(const bf16x8*)(W2f + (size_t)(s * 2 + half) * 512 + (ct2 * 32 + l31) * 8);
        acc2 = __builtin_amdgcn_mfma_f32_32x32x16_bf16(a, b, acc2, 0, 0, 0);
    }

    // pooling partials: butterfly over 32 cols, pool-exchange across col tiles
    float bb = b2[ct2 * 32 + l31];
    float pwv = pw[ct2 * 32 + l31];
    float pbv = pb[0];
    float hreg[16];
    #pragma unroll
    for (int reg = 0; reg < 16; ++reg) {
        float h = acc2[reg] + bb;
        hreg[reg] = h;
        float d = h * pwv;
        d += __shfl_xor(d, 1, 64);
        d += __shfl_xor(d, 2, 64);
        d += __shfl_xor(d, 4, 64);
        d += __shfl_xor(d, 8, 64);
        d += __shfl_xor(d, 16, 64);
        if (l31 == 0) pools[rt2][ct2][half][reg] = d;
    }
    __syncthreads();
    #pragma unroll
    for (int reg = 0; reg < 16; ++reg) {
        int rowin = (reg & 3) + 8 * (reg >> 2) + 4 * half;
        int row = bm + rt2 * 32 + rowin;
        float d = pools[rt2][0][half][reg] + pools[rt2][1][half][reg];
        float sg = 1.f / (1.f + __expf(-(d + pbv)));
        float h = hreg[reg];
        if (row < M) {
            float dv = dinv[row];
            out[(size_t)row * 64 + ct2 * 32 + l31] = sg * h;
            g[(size_t)row * 64 + ct2 * 32 + l31]   = f2bf(dv * h);
        }
    }
}

// ---- one hop (r12): source-range sweep. Wave owns DPW dests; 32 lanes per
//      row (dword = 2 ch per lane), 2 edge slots (g) per instr. acc persists
//      in registers across the 8 range phases; epilogue fused. ----
__global__ __launch_bounds__(256, 5) void spmm2_kernel(
        const int* __restrict__ offs2, const int* __restrict__ src,
        const float* __restrict__ dinv,
        const unsigned* __restrict__ gin,      // bf16x2 dwords, 32/row
        unsigned* __restrict__ gout,
        float* __restrict__ out,
        const float* __restrict__ pw, const float* __restrict__ pb,
        int n) {
    int wid = blockIdx.x * 4 + (threadIdx.x >> 6);
    int lane = threadIdx.x & 63;
    int g = lane >> 5;          // edge slot (0/1)
    int q = lane & 31;          // dword index -> channels 2q, 2q+1
    int base = wid * DPW;
    if (base >= n) return;

    float accA[DPW], accB[DPW];
    #pragma unroll
    for (int j = 0; j < DPW; ++j) { accA[j] = 0.f; accB[j] = 0.f; }

    for (int r = 0; r < NR; ++r) {
        size_t kb = (size_t)r * n + base;
        int e0 = __builtin_amdgcn_readfirstlane(offs2[kb]);
        #pragma unroll
        for (int j = 0; j < DPW; ++j) {
            if (base + j < n) {
                int e1 = __builtin_amdgcn_readfirstlane(offs2[kb + j + 1]);
                for (int e = e0; e < e1; e += 4) {
                    #pragma unroll
                    for (int u = 0; u < 2; ++u) {
                        int ei = e + u * 2 + g;
                        int ec = (ei < e1) ? ei : (e1 - 1);
                        unsigned mm = (ei < e1) ? 0xffffffffu : 0u;
                        int s = src[ec];
                        unsigned v = gin[(size_t)s * 32 + q] & mm;
                        accA[j] += bflo(v);
                        accB[j] += bfhi(v);
                    }
                }
                e0 = e1;
            }
        }
    }

    float pbv = pb[0];
    float2 pv = *(const float2*)(pw + q * 2);
    #pragma unroll
    for (int j = 0; j < DPW; ++j) {
        int c = base + j;
        if (c >= n) break;
        float a0 = accA[j], a1 = accB[j];
        a0 += __shfl_xor(a0, 32, 64);
        a1 += __shfl_xor(a1, 32, 64);
        unsigned sv = gin[(size_t)c * 32 + q];   // self-loop (prescaled by dinv)
        a0 += bflo(sv); a1 += bfhi(sv);
        float dc = dinv[c];
        float h0 = dc * a0, h1 = dc * a1;
        float d = h0 * pv.x + h1 * pv.y;
        d += __shfl_xor(d, 1, 64);
        d += __shfl_xor(d, 2, 64);
        d += __shfl_xor(d, 4, 64);
        d += __shfl_xor(d, 8, 64);
        d += __shfl_xor(d, 16, 64);
        float sg = 1.f / (1.f + __expf(-(d + pbv)));
        if (g == 0) {
            gout[(size_t)c * 32 + q] =
                (unsigned)f2bf(dc * h0) | ((unsigned)f2bf(dc * h1) << 16);
            float2 o = *(float2*)(out + (size_t)c * 64 + q * 2);
            o.x += sg * h0; o.y += sg * h1;
            *(float2*)(out + (size_t)c * 64 + q * 2) = o;
        }
    }
}

extern "C" void kernel_launch(void* const* d_in, const int* in_sizes, int n_in,
                              void* d_out, int out_size, void* d_ws, size_t ws_size,
                              hipStream_t stream) {
    const float* x  = (const float*)d_in[0];
    const int* eidx = (const int*)d_in[1];
    const float* W1 = (const float*)d_in[2];
    const float* b1 = (const float*)d_in[3];
    const float* W2 = (const float*)d_in[4];
    const float* b2 = (const float*)d_in[5];
    const float* pw = (const float*)d_in[6];
    const float* pb = (const float*)d_in[7];
    float* out = (float*)d_out;

    const int N = in_sizes[0] / 256;
    const int E = in_sizes[1] / 2;
    const int NB = (N + 255) >> 8;              // buckets of 256 dest nodes
    const int EPB = (E + NBLK - 1) / NBLK;      // edges per passA/passB block
    const int M = NB * NBLK;                    // blk_cnt entries
    const int N8 = N * NR;                      // (range, dest) keys

    size_t woff = 0;
    auto alloc = [&](size_t bytes) -> void* {
        void* p = (char*)d_ws + woff;
        woff += (bytes + 255) & ~(size_t)255;
        return p;
    };
    int*   sflag   = (int*)alloc(4);
    int*   cnt2    = (int*)alloc((size_t)N8 * 4);
    float* dinv    = (float*)alloc((size_t)N * 4);
    int*   offs2   = (int*)alloc(((size_t)N8 + 1) * 4);
    int*   bsums   = (int*)alloc(1024 * 4);
    int*   bsums2  = (int*)alloc(1024 * 4);
    int*   pbase   = (int*)alloc(((size_t)M + 1) * 4);
    int*   csr_src = (int*)alloc((size_t)E * 4);
    int2*  pairs   = (int2*)alloc((size_t)E * 8);
    unsigned short* W1f = (unsigned short*)alloc((size_t)256 * 256 * 2);
    unsigned short* W2f = (unsigned short*)alloc((size_t)64 * 256 * 2);
    unsigned short* gA = (unsigned short*)alloc((size_t)N * 64 * 2);
    unsigned short* gB = (unsigned short*)alloc((size_t)N * 64 * 2);

    detect_kernel<<<1, 256, 0, stream>>>((const unsigned*)eidx, sflag);

    // build: histogram -> scan -> pair scatter -> (range,node) counts -> offs2 -> CSR
    passA_kernel<<<NBLK, 256, 0, stream>>>(eidx, sflag, pbase, E, NB, EPB);
    int nb2 = (M + 1023) / 1024;
    scan1_kernel<<<nb2, 256, 0, stream>>>(pbase, pbase, bsums2, M);
    scan2g_kernel<<<1, 256, 0, stream>>>(bsums2, nb2);
    scan3_kernel<<<nb2, 256, 0, stream>>>(pbase, bsums2, M, E);
    passB_kernel<<<NBLK, 256, 0, stream>>>(eidx, sflag, pbase, pairs, E, NB, EPB);
    passD2_kernel<<<NB, 256, 0, stream>>>(pairs, pbase, cnt2, N, NB);
    dinv2_kernel<<<(N + 255) / 256, 256, 0, stream>>>(cnt2, dinv, N);
    int nb1 = (N8 + 1023) / 1024;
    scan1_kernel<<<nb1, 256, 0, stream>>>(cnt2, offs2, bsums, N8);
    scan2g_kernel<<<1, 256, 0, stream>>>(bsums, nb1);
    scan3_kernel<<<nb1, 256, 0, stream>>>(offs2, bsums, N8, E);
    passC2_kernel<<<NB, 256, 0, stream>>>(pairs, pbase, offs2, csr_src, N, NB);

    // MLP (fused) + hop0
    wconv_kernel<<<(256 * 256 + 255) / 256, 256, 0, stream>>>(W1, W1f, 256, 256);
    wconv_kernel<<<(64 * 256 + 255) / 256, 256, 0, stream>>>(W2, W2f, 256, 64);
    int gb = (N + 63) / 64;
    mlp_fused<<<gb, 256, 0, stream>>>(x, W1f, b1, W2f, b2, dinv, pw, pb,
                                      out, gA, N);

    // propagation + fused pooling: range-swept spmm, co-resident grid
    int nblk2 = (N + DPW * 4 - 1) / (DPW * 4);
    unsigned short* gin = gA;
    unsigned short* gout = gB;
    for (int k = 0; k < 10; ++k) {
        spmm2_kernel<<<nblk2, 256, 0, stream>>>(offs2, csr_src, dinv,
                                                (const unsigned*)gin, (unsigned*)gout,
                                                out, pw, pb, N);
        unsigned short* t = gin; gin = gout; gout = t;
    }
}